// Round 1
// baseline (25835.226 us; speedup 1.0000x reference)
//
#include <hip/hip_runtime.h>
#include <hip/hip_bf16.h>

typedef short short8 __attribute__((ext_vector_type(8)));
typedef float f32x4 __attribute__((ext_vector_type(4)));
typedef unsigned short us4 __attribute__((ext_vector_type(4)));

#define AS1 __attribute__((address_space(1)))
#define AS3 __attribute__((address_space(3)))

static __device__ __forceinline__ void gl_lds16(const void* g, void* l) {
    __builtin_amdgcn_global_load_lds((const AS1 void*)g, (AS3 void*)l, 16, 0, 0);
}

static __device__ __forceinline__ unsigned short f2bf(float x) {
    __hip_bfloat16 b = __float2bfloat16(x);
    return __builtin_bit_cast(unsigned short, b);
}

// ---------------- f32 -> bf16 convert, 4 elems/thread, exact grid ----------------
__global__ void cvt_bf16_kernel(const float* __restrict__ src, unsigned short* __restrict__ dst) {
    size_t i = (size_t)blockIdx.x * 256 + threadIdx.x;
    float4 v = ((const float4*)src)[i];
    us4 o = { f2bf(v.x), f2bf(v.y), f2bf(v.z), f2bf(v.w) };
    ((us4*)dst)[i] = o;
}

// ---------------- embedding gather -> bf16, one block per token ----------------
__global__ void embed_kernel(const int* __restrict__ x, const float* __restrict__ embed,
                             unsigned short* __restrict__ Xb) {
    int m = blockIdx.x;
    int tok = x[m];
    float4 v = ((const float4*)(embed + (size_t)tok * 1024))[threadIdx.x];
    us4 o = { f2bf(v.x), f2bf(v.y), f2bf(v.z), f2bf(v.w) };
    ((us4*)(Xb + (size_t)m * 1024))[threadIdx.x] = o;
}

// ---------------- C[M,N] fp32 = A[M,K]bf16 * B[N,K]bf16^T + bias0 + bias1 ----------------
// 128x128 tile, BK=64, 256 threads = 4 waves (2x2 of 64x64), mfma 16x16x32 bf16,
// staging via global_load_lds width=16 (m97 structure).
__global__ __launch_bounds__(256) void gemm_bt_kernel(
    const unsigned short* __restrict__ A, const unsigned short* __restrict__ B,
    float* __restrict__ C, const float* __restrict__ bias0, const float* __restrict__ bias1,
    int M, int N, int K)
{
    __shared__ __align__(16) unsigned short As[128 * 64];
    __shared__ __align__(16) unsigned short Bs[128 * 64];
    const int tid = threadIdx.x;
    const int l = tid & 63, w = tid >> 6;
    const int wy = w >> 1, wx = w & 1;
    const int m0 = blockIdx.y * 128, n0 = blockIdx.x * 128;
    const int lm = l & 15, lq = l >> 4;
    f32x4 acc[4][4] = {};

    for (int kb = 0; kb < K; kb += 64) {
        __syncthreads();   // protect LDS from previous iteration's readers
        #pragma unroll
        for (int rd = 0; rd < 4; ++rd) {
            int c = rd * 256 + tid;          // 8-elem chunk id, lane-linear per wave
            int row = c >> 3, kc = c & 7;
            gl_lds16(A + (size_t)(m0 + row) * K + kb + kc * 8, As + c * 8);
            gl_lds16(B + (size_t)(n0 + row) * K + kb + kc * 8, Bs + c * 8);
        }
        __syncthreads();   // drains vmcnt (global_load_lds) per barrier semantics
        #pragma unroll
        for (int ks = 0; ks < 2; ++ks) {
            const int kk = ks * 32 + lq * 8;
            short8 a[4], b[4];
            #pragma unroll
            for (int i = 0; i < 4; ++i)
                a[i] = *(const short8*)(As + (wy * 64 + i * 16 + lm) * 64 + kk);
            #pragma unroll
            for (int i = 0; i < 4; ++i)
                b[i] = *(const short8*)(Bs + (wx * 64 + i * 16 + lm) * 64 + kk);
            #pragma unroll
            for (int mt = 0; mt < 4; ++mt)
                #pragma unroll
                for (int nt = 0; nt < 4; ++nt)
                    acc[mt][nt] = __builtin_amdgcn_mfma_f32_16x16x32_bf16(a[mt], b[nt], acc[mt][nt], 0, 0, 0);
        }
    }
    // epilogue: C/D layout col = lane&15, row = (lane>>4)*4 + reg
    #pragma unroll
    for (int nt = 0; nt < 4; ++nt) {
        int n = n0 + wx * 64 + nt * 16 + lm;
        float bv = 0.f;
        if (bias0) bv += bias0[n];
        if (bias1) bv += bias1[n];
        #pragma unroll
        for (int mt = 0; mt < 4; ++mt) {
            size_t base = (size_t)(m0 + wy * 64 + mt * 16 + lq * 4) * N + n;
            C[base]               = acc[mt][nt][0] + bv;
            C[base + (size_t)N]   = acc[mt][nt][1] + bv;
            C[base + 2*(size_t)N] = acc[mt][nt][2] + bv;
            C[base + 3*(size_t)N] = acc[mt][nt][3] + bv;
        }
    }
}

// ---------------- persistent LSTM layer: 256 blocks x 256 threads, 1 block/CU ----------------
// Block owns 4 h-columns (16 Whh gate-rows). Whh slice pre-loaded into MFMA A-frags
// (registers). z = Whh_slice @ h^T via mfma 16x16x32 (M=16 rows, N=batch in cols 0..3,
// K split 256 per wave, cross-wave reduce in LDS). h double-buffered bf16 in global.
// One hierarchical grid barrier per timestep (8 group counters -> root).
__global__ __launch_bounds__(256) void lstm_kernel(
    const float* __restrict__ pre,            // (4,1024,4096) fp32, biases already added
    const unsigned short* __restrict__ Whh,   // (4096,1024) bf16
    unsigned short* __restrict__ hbuf,        // [2][4][1024] bf16, pre-zeroed
    unsigned* __restrict__ grp,               // [8][1024] zeroed
    unsigned* __restrict__ root,              // [1024] zeroed
    unsigned short* __restrict__ hs_out)      // (4,1024,1024) bf16
{
    const int tid = threadIdx.x;
    const int l = tid & 63, w = tid >> 6;
    const int blk = blockIdx.x;
    const int r = l & 15;        // A-frag m index / (as n) output col
    const int q = l >> 4;        // quad
    const int koff = w * 256;    // this wave's K slice

    // Preload A-frags: A[m=lane&15][k=quad*8+j]; row m -> Whh row (m>>2)*1024 + blk*4 + (m&3)
    short8 af[8];
    {
        const size_t rowoff = ((size_t)((r >> 2) * 1024 + blk * 4 + (r & 3))) * 1024;
        #pragma unroll
        for (int s = 0; s < 8; ++s)
            af[s] = *(const short8*)(Whh + rowoff + koff + s * 32 + q * 8);
    }

    __shared__ float zp[4][64];               // per-wave partial z: [wave][row*4 + batch]
    const int b16 = tid & 3, cl16 = tid >> 2; // valid for tid<16
    const int col16 = blk * 4 + cl16;
    float c_state = 0.f;

    for (int t = 0; t < 1024; ++t) {
        // prefetch pre-activations for this step (overlaps h loads + MFMA)
        float pv0, pv1, pv2, pv3;
        if (tid < 16) {
            const float* p = pre + (((size_t)(b16 * 1024 + t)) << 12) + col16;
            pv0 = p[0]; pv1 = p[1024]; pv2 = p[2048]; pv3 = p[3072];
        }
        // B-frags: B[n=lane&15][k=quad*8+j] = h[batch n&3][k]
        const unsigned short* hr = hbuf + (t & 1) * 4096 + (l & 3) * 1024 + koff + q * 8;
        f32x4 acc = {0.f, 0.f, 0.f, 0.f};
        #pragma unroll
        for (int s = 0; s < 8; ++s) {
            short8 bf = *(const short8*)(hr + s * 32);
            acc = __builtin_amdgcn_mfma_f32_16x16x32_bf16(af[s], bf, acc, 0, 0, 0);
        }
        if (r < 4) {                          // cols 0..3 = batches; D row = q*4+reg
            #pragma unroll
            for (int i = 0; i < 4; ++i)
                zp[w][(q * 4 + i) * 4 + r] = acc[i];
        }
        __syncthreads();
        if (tid < 16) {
            float z[4];
            #pragma unroll
            for (int g = 0; g < 4; ++g) {
                int row = g * 4 + cl16;
                z[g] = zp[0][row*4+b16] + zp[1][row*4+b16] + zp[2][row*4+b16] + zp[3][row*4+b16];
            }
            z[0] += pv0; z[1] += pv1; z[2] += pv2; z[3] += pv3;
            float ig = 1.f / (1.f + __expf(-z[0]));
            float fg = 1.f / (1.f + __expf(-z[1]));
            float gg = tanhf(z[2]);
            float og = 1.f / (1.f + __expf(-z[3]));
            c_state = fg * c_state + ig * gg;
            float h = og * tanhf(c_state);
            unsigned short hu = f2bf(h);
            hbuf[((t + 1) & 1) * 4096 + b16 * 1024 + col16] = hu;
            hs_out[((size_t)(b16 * 1024 + t) << 10) + col16] = hu;
        }
        // grid barrier (double-buffered h => one barrier per step is race-free)
        __syncthreads();
        if (tid == 0) {
            __threadfence();                               // release: flush h to L3 (cross-XCD)
            unsigned old = atomicAdd(grp + ((blk >> 5) * 1024 + t), 1u);
            if (old == 31u) atomicAdd(root + t, 1u);
            int guard = 0;
            while (__hip_atomic_load(root + t, __ATOMIC_RELAXED, __HIP_MEMORY_SCOPE_AGENT) < 8u) {
                __builtin_amdgcn_s_sleep(1);
                if (++guard > (1 << 14)) break;            // anti-hang safeguard
            }
            __threadfence();                               // acquire: invalidate L1/L2
        }
        __syncthreads();
    }
}

extern "C" void kernel_launch(void* const* d_in, const int* in_sizes, int n_in,
                              void* d_out, int out_size, void* d_ws, size_t ws_size,
                              hipStream_t stream)
{
    const int*   x     = (const int*)d_in[0];
    const float* embed = (const float*)d_in[1];
    const float* Wproj = (const float*)d_in[2];
    const float* bproj = (const float*)d_in[3];
    const float* Wih0  = (const float*)d_in[4];
    const float* Whh0  = (const float*)d_in[5];
    const float* bih0  = (const float*)d_in[6];
    const float* bhh0  = (const float*)d_in[7];
    const float* Wih1  = (const float*)d_in[8];
    const float* Whh1  = (const float*)d_in[9];
    const float* bih1  = (const float*)d_in[10];
    const float* bhh1  = (const float*)d_in[11];

    char* ws = (char*)d_ws;
    unsigned* grp0  = (unsigned*)(ws);                  // 8*1024*4 = 32KB
    unsigned* grp1  = (unsigned*)(ws + 32768);          // 32KB
    unsigned* root0 = (unsigned*)(ws + 65536);          // 4KB
    unsigned* root1 = (unsigned*)(ws + 65536 + 4096);   // 4KB
    unsigned short* hbuf0 = (unsigned short*)(ws + 131072);          // 16KB
    unsigned short* hbuf1 = (unsigned short*)(ws + 131072 + 16384);  // 16KB

    size_t off = (size_t)1 << 20;
    auto alloc = [&](size_t bytes) { void* p = ws + off; off += (bytes + 255) & ~(size_t)255; return p; };
    unsigned short* Xb     = (unsigned short*)alloc(4096ull * 1024 * 2);
    unsigned short* hs0    = (unsigned short*)alloc(4096ull * 1024 * 2);
    unsigned short* hs1    = (unsigned short*)alloc(4096ull * 1024 * 2);
    unsigned short* wih0b  = (unsigned short*)alloc(4096ull * 1024 * 2);
    unsigned short* whh0b  = (unsigned short*)alloc(4096ull * 1024 * 2);
    unsigned short* wih1b  = (unsigned short*)alloc(4096ull * 1024 * 2);
    unsigned short* whh1b  = (unsigned short*)alloc(4096ull * 1024 * 2);
    unsigned short* wprojb = (unsigned short*)alloc(32000ull * 1024 * 2);
    float* pre             = (float*)alloc(4096ull * 4096 * 4);      // shared by both layers

    // zero barrier counters + h double-buffers (ws is poisoned 0xAA before every call)
    hipMemsetAsync(d_ws, 0, 163840, stream);

    cvt_bf16_kernel<<<4096, 256, 0, stream>>>(Wih0, wih0b);
    cvt_bf16_kernel<<<4096, 256, 0, stream>>>(Whh0, whh0b);
    cvt_bf16_kernel<<<4096, 256, 0, stream>>>(Wih1, wih1b);
    cvt_bf16_kernel<<<4096, 256, 0, stream>>>(Whh1, whh1b);
    cvt_bf16_kernel<<<32000, 256, 0, stream>>>(Wproj, wprojb);
    embed_kernel<<<4096, 256, 0, stream>>>(x, embed, Xb);

    // layer 0
    gemm_bt_kernel<<<dim3(32, 32), 256, 0, stream>>>(Xb, wih0b, pre, bih0, bhh0, 4096, 4096, 1024);
    lstm_kernel<<<256, 256, 0, stream>>>(pre, whh0b, hbuf0, grp0, root0, hs0);
    // layer 1
    gemm_bt_kernel<<<dim3(32, 32), 256, 0, stream>>>(hs0, wih1b, pre, bih1, bhh1, 4096, 4096, 1024);
    lstm_kernel<<<256, 256, 0, stream>>>(pre, whh1b, hbuf1, grp1, root1, hs1);
    // projection
    gemm_bt_kernel<<<dim3(250, 32), 256, 0, stream>>>(hs1, wprojb, (float*)d_out, bproj, nullptr, 4096, 32000, 1024);
}